// Round 6
// baseline (270.530 us; speedup 1.0000x reference)
//
#include <hip/hip_runtime.h>

#define D 128
#define TN 64
#define NC 8  // privatization copies (#XCDs)

typedef __attribute__((ext_vector_type(8))) short short8;
typedef __attribute__((ext_vector_type(4))) float f32x4;

__device__ __forceinline__ unsigned int bf16rne(float f) {
  unsigned int b = __float_as_uint(f);
  return (b + 0x7fffu + ((b >> 16) & 1u)) >> 16;
}
__device__ __forceinline__ float bf2f(unsigned int u) {
  return __uint_as_float(u << 16);
}

// ---- one-time: W[r][k][c] (+loopW at R) -> bf16, transposed [c][k], XOR-swizzled ----
__global__ __launch_bounds__(256) void rgc_prep_w(
    const float* __restrict__ W, const float* __restrict__ loopW,
    unsigned short* __restrict__ WT, int R)
{
  int tid = blockIdx.x * 256 + threadIdx.x;
  int s = tid >> 14;
  if (s > R) return;
  int rem = tid & 16383;
  int k = rem >> 7;
  int c = rem & 127;
  float v = (s < R) ? W[(size_t)s * D * D + k * D + c] : loopW[k * D + c];
  unsigned int u = bf16rne(v);
  unsigned int off = ((unsigned int)(c * D + k) * 2u) ^ (((unsigned int)(c & 7)) << 4);
  *(unsigned short*)((char*)WT + (size_t)s * D * D * 2 + off) = (unsigned short)u;
}

// ---- one-time: x -> bf16 row-major ----
__global__ __launch_bounds__(256) void rgc_prep_x(
    const float* __restrict__ x, unsigned short* __restrict__ xb, long long total8)
{
  long long i = (long long)blockIdx.x * 256 + threadIdx.x;
  if (i >= total8) return;
  float4 v0 = ((const float4*)x)[i * 2];
  float4 v1 = ((const float4*)x)[i * 2 + 1];
  uint4 u;
  u.x = bf16rne(v0.x) | (bf16rne(v0.y) << 16);
  u.y = bf16rne(v0.z) | (bf16rne(v0.w) << 16);
  u.z = bf16rne(v1.x) | (bf16rne(v1.y) << 16);
  u.w = bf16rne(v1.z) | (bf16rne(v1.w) << 16);
  ((uint4*)xb)[i] = u;
}

// ---- hist: one XCD-local atomic per edge into cnt8[(k*G+g)*N + d] ----
__global__ __launch_bounds__(256) void rgc_hist(
    const int* __restrict__ dst, int* __restrict__ cnt8,
    int N, int E, int G, int rel0)
{
  int g = blockIdx.y;
  int e = blockIdx.x * 256 + threadIdx.x;
  if (e >= E) return;
  int k = (blockIdx.x + gridDim.x * blockIdx.y) & (NC - 1);
  int d = dst[(size_t)(rel0 + g) * E + e];
  atomicAdd(&cnt8[((size_t)k * G + g) * N + d], 1);
}

// ---- per-chunk sums: one wave per (copy,rel,tile) chunk of 64 nodes ----
__global__ __launch_bounds__(256) void rgc_chunksum(
    const int* __restrict__ cnt8, int* __restrict__ tcnt8,
    int N, int ntiles, int nchunks)
{
  int wv = threadIdx.x >> 6, lane = threadIdx.x & 63;
  int chunk = blockIdx.x * 4 + wv;
  if (chunk >= nchunks) return;
  int row = chunk / ntiles, tile = chunk - row * ntiles;
  int node = tile * TN + lane;
  int v = (node < N) ? cnt8[(size_t)row * N + node] : 0;
#pragma unroll
  for (int o = 32; o > 0; o >>= 1) v += __shfl_xor(v, o, 64);
  if (lane == 0) tcnt8[chunk] = v;
}

// ---- exclusive scan over M chunk counts (single block, carry loop; M <= ~64K) ----
__global__ __launch_bounds__(1024) void rgc_scan(
    const int* __restrict__ cnt, int* __restrict__ ptr, int M, int total)
{
  __shared__ int buf[1024];
  __shared__ int carry_s;
  int tid = threadIdx.x;
  if (tid == 0) carry_s = 0;
  __syncthreads();
  for (int base = 0; base < M; base += 8192) {
    int c0 = carry_s;
    int v[8];
    int s = 0;
#pragma unroll
    for (int j = 0; j < 8; j++) {
      int i = base + tid * 8 + j;
      v[j] = (i < M) ? cnt[i] : 0;
      s += v[j];
    }
    buf[tid] = s;
    __syncthreads();
    for (int off = 1; off < 1024; off <<= 1) {
      int t = (tid >= off) ? buf[tid - off] : 0;
      __syncthreads();
      buf[tid] += t;
      __syncthreads();
    }
    int run = c0 + buf[tid] - s;
#pragma unroll
    for (int j = 0; j < 8; j++) {
      int i = base + tid * 8 + j;
      if (i < M) ptr[i] = run;
      run += v[j];
    }
    int tot = buf[1023];
    __syncthreads();
    if (tid == 0) carry_s = c0 + tot;
    __syncthreads();
  }
  if (tid == 0) ptr[M] = total;
}

// ---- per-(copy,node) start offsets: tptr8[chunk] + within-chunk prefix ----
__global__ __launch_bounds__(256) void rgc_offsets(
    const int* __restrict__ cnt8, const int* __restrict__ tptr8,
    int* __restrict__ off8, int N, int ntiles, int nchunks)
{
  int wv = threadIdx.x >> 6, lane = threadIdx.x & 63;
  int chunk = blockIdx.x * 4 + wv;
  if (chunk >= nchunks) return;
  int row = chunk / ntiles, tile = chunk - row * ntiles;
  int node = tile * TN + lane;
  int deg = (node < N) ? cnt8[(size_t)row * N + node] : 0;
  int v = deg;
#pragma unroll
  for (int o = 1; o < 64; o <<= 1) {
    int t = __shfl_up(v, o, 64);
    if (lane >= o) v += t;
  }
  if (node < N) off8[(size_t)row * N + node] = tptr8[chunk] + (v - deg);
}

// ---- fill: scatter src ids into copy-major node-contiguous lists ----
__global__ __launch_bounds__(256) void rgc_fill(
    const int* __restrict__ src, const int* __restrict__ dst,
    int* __restrict__ off8, int* __restrict__ esrc,
    int N, int E, int G, int rel0)
{
  int g = blockIdx.y;
  int e = blockIdx.x * 256 + threadIdx.x;
  if (e >= E) return;
  int k = (blockIdx.x + gridDim.x * blockIdx.y) & (NC - 1);
  int d = dst[(size_t)(rel0 + g) * E + e];
  int pos = atomicAdd(&off8[((size_t)k * G + g) * N + d], 1);
  esrc[pos] = src[(size_t)(rel0 + g) * E + e];
}

// ---- aggregation: register-only gather -> mean -> swizzled bf16 Ahat tile ----
// off8 now holds END offsets (post-fill); start = end - cnt.
__global__ __launch_bounds__(256) void rgc_agg(
    const unsigned short* __restrict__ xb, const int* __restrict__ cnt8,
    const int* __restrict__ off8, const int* __restrict__ esrc,
    unsigned short* __restrict__ Ahat, int N, int ntiles, int G)
{
  __shared__ int lcnt[NC][TN];
  __shared__ int lend[NC][TN];
  int tx = threadIdx.x;
  int tile = blockIdx.x;
  int g = blockIdx.y;
  int node0 = tile * TN;

#pragma unroll
  for (int idx = tx; idx < NC * TN; idx += 256) {
    int k = idx >> 6, row = idx & 63;
    int node = node0 + row;
    size_t p = ((size_t)k * G + g) * N + node;
    lcnt[k][row] = (node < N) ? cnt8[p] : 0;
    lend[k][row] = (node < N) ? off8[p] : 0;
  }
  __syncthreads();

  int grp = tx >> 4, c = tx & 15;
  char* dstp = (char*)(Ahat + ((size_t)tile * G + g) * (TN * D));

#pragma unroll
  for (int t = 0; t < 4; t++) {
    int row = grp * 4 + t;
    float acc[8];
#pragma unroll
    for (int q = 0; q < 8; q++) acc[q] = 0.f;
    int deg = 0;
#pragma unroll
    for (int k = 0; k < NC; k++) {
      int cnt = lcnt[k][row];
      int st = lend[k][row] - cnt;
      deg += cnt;
      for (int j = 0; j < cnt; j++) {
        int s = esrc[st + j];
        uint4 u = ((const uint4*)(xb + (size_t)s * D))[c];
        acc[0] += bf2f(u.x & 0xffffu); acc[1] += bf2f(u.x >> 16);
        acc[2] += bf2f(u.y & 0xffffu); acc[3] += bf2f(u.y >> 16);
        acc[4] += bf2f(u.z & 0xffffu); acc[5] += bf2f(u.z >> 16);
        acc[6] += bf2f(u.w & 0xffffu); acc[7] += bf2f(u.w >> 16);
      }
    }
    float sc = 1.0f / fmaxf((float)deg, 1.0f);
    uint4 o;
    o.x = bf16rne(acc[0] * sc) | (bf16rne(acc[1] * sc) << 16);
    o.y = bf16rne(acc[2] * sc) | (bf16rne(acc[3] * sc) << 16);
    o.z = bf16rne(acc[4] * sc) | (bf16rne(acc[5] * sc) << 16);
    o.w = bf16rne(acc[6] * sc) | (bf16rne(acc[7] * sc) << 16);
    unsigned int off =
        ((unsigned int)(row * 256 + c * 16)) ^ (((unsigned int)(row & 7)) << 4);
    *(uint4*)(dstp + off) = o;
  }
}

// ---- GEMM: out_tile = [relu](prior + sum_s Ahat_s @ W_s [+ xb @ loopW]) ----
__global__ __launch_bounds__(256) void rgc_gemm(
    const unsigned short* __restrict__ xb, const unsigned short* __restrict__ WT,
    const unsigned short* __restrict__ Ahat, float* __restrict__ out,
    int N, int Gpass, int rel0, int R, int flags)
{
  __shared__ char Ab[TN * D * 2];  // 16 KB
  __shared__ char Wb[D * D * 2];   // 32 KB

  int tx = threadIdx.x;
  int tile = blockIdx.x;
  int node0 = tile * TN;
  int lane = tx & 63;
  int w = tx >> 6;

  f32x4 acc[8];
#pragma unroll
  for (int i = 0; i < 8; i++) acc[i] = (f32x4){0.f, 0.f, 0.f, 0.f};

  int S = Gpass + ((flags & 2) ? 1 : 0);
  for (int s = 0; s < S; s++) {
    bool is_loop = (s == Gpass);
    int widx = is_loop ? R : (rel0 + s);
    if (!is_loop) {
      const float4* asrc = (const float4*)(Ahat + ((size_t)tile * Gpass + s) * (TN * D));
#pragma unroll
      for (int i = 0; i < 4; i++)
        ((float4*)Ab)[tx + i * 256] = asrc[tx + i * 256];
    } else {
#pragma unroll
      for (int it = 0; it < 4; it++) {
        int i = tx + it * 256;
        int row = i >> 4, c16 = i & 15;
        int node = node0 + row;
        uint4 u = make_uint4(0, 0, 0, 0);
        if (node < N) u = ((const uint4*)(xb + (size_t)node * D))[c16];
        unsigned int off =
            ((unsigned int)(row * 256 + c16 * 16)) ^ (((unsigned int)(row & 7)) << 4);
        *(uint4*)(Ab + off) = u;
      }
    }
    const float4* wsrc = (const float4*)(WT + (size_t)widx * D * D);
#pragma unroll
    for (int i = 0; i < 8; i++)
      ((float4*)Wb)[tx + i * 256] = wsrc[tx + i * 256];
    __syncthreads();

    int rA = w * 16 + (lane & 15);
    unsigned int mA = (unsigned int)((rA & 7) << 4);
    unsigned int kof = (unsigned int)((lane >> 4) * 16);
    short8 afr[4];
#pragma unroll
    for (int kk = 0; kk < 4; kk++)
      afr[kk] = *(const short8*)(Ab + rA * 256 + (((unsigned int)(kk * 64) + kof) ^ mA));
#pragma unroll
    for (int ct = 0; ct < 8; ct++) {
      int rB = ct * 16 + (lane & 15);
      unsigned int mB = (unsigned int)((rB & 7) << 4);
#pragma unroll
      for (int kk = 0; kk < 4; kk++) {
        short8 b = *(const short8*)(Wb + rB * 256 + (((unsigned int)(kk * 64) + kof) ^ mB));
        acc[ct] = __builtin_amdgcn_mfma_f32_16x16x32_bf16(afr[kk], b, acc[ct], 0, 0, 0);
      }
    }
    __syncthreads();
  }

  int colb = lane & 15;
  int rowb = (lane >> 4) * 4;
#pragma unroll
  for (int ct = 0; ct < 8; ct++) {
#pragma unroll
    for (int j = 0; j < 4; j++) {
      int node = node0 + w * 16 + rowb + j;
      if (node >= N) continue;
      float* op = out + (size_t)node * D + ct * 16 + colb;
      float r = acc[ct][j];
      if (!(flags & 1)) r += *op;
      if (flags & 2) r = fmaxf(r, 0.f);
      *op = r;
    }
  }
}

extern "C" void kernel_launch(void* const* d_in, const int* in_sizes, int n_in,
                              void* d_out, int out_size, void* d_ws, size_t ws_size,
                              hipStream_t stream)
{
  const float* x     = (const float*)d_in[0];
  const float* W     = (const float*)d_in[1];
  const float* loopW = (const float*)d_in[2];
  const int*   src   = (const int*)d_in[3];
  const int*   dst   = (const int*)d_in[4];
  float* out = (float*)d_out;

  int N = in_sizes[0] / D;        // 100000
  int R = in_sizes[1] / (D * D);  // 4
  int E = in_sizes[3] / R;        // 160000
  int ntiles = (N + TN - 1) / TN;

  // layout: cnt8 | off8 | tcnt8 | tptr8 | esrc | WT | xb | Ahat
  size_t o_cnt8  = 0;
  size_t o_off8  = (o_cnt8 + (size_t)NC * R * N * 4 + 15) & ~(size_t)15;
  size_t o_tcnt8 = (o_off8 + (size_t)NC * R * N * 4 + 15) & ~(size_t)15;
  size_t o_tptr8 = (o_tcnt8 + (size_t)NC * R * ntiles * 4 + 15) & ~(size_t)15;
  size_t o_esrc  = (o_tptr8 + ((size_t)NC * R * ntiles + 1) * 4 + 15) & ~(size_t)15;
  size_t o_wt    = (o_esrc + (size_t)R * E * 4 + 15) & ~(size_t)15;
  size_t o_xb    = (o_wt + (size_t)(R + 1) * D * D * 2 + 15) & ~(size_t)15;
  size_t o_ahat  = (o_xb + (size_t)N * D * 2 + 15) & ~(size_t)15;

  char* wsb = (char*)d_ws;
  int*  cnt8  = (int*)(wsb + o_cnt8);
  int*  off8  = (int*)(wsb + o_off8);
  int*  tcnt8 = (int*)(wsb + o_tcnt8);
  int*  tptr8 = (int*)(wsb + o_tptr8);
  int*  esrc  = (int*)(wsb + o_esrc);
  unsigned short* WT   = (unsigned short*)(wsb + o_wt);
  unsigned short* xb   = (unsigned short*)(wsb + o_xb);
  unsigned short* Ahat = (unsigned short*)(wsb + o_ahat);

  int G = R;
  while (G > 1 && o_ahat + (size_t)ntiles * G * TN * D * 2 > ws_size) G--;

  rgc_prep_w<<<((R + 1) * D * D + 255) / 256, 256, 0, stream>>>(W, loopW, WT, R);
  long long total8 = (long long)N * D / 8;
  rgc_prep_x<<<(int)((total8 + 255) / 256), 256, 0, stream>>>(x, xb, total8);

  for (int rel0 = 0; rel0 < R; rel0 += G) {
    int g = (R - rel0 < G) ? (R - rel0) : G;
    hipMemsetAsync(cnt8, 0, (size_t)NC * g * N * 4, stream);
    dim3 egrid((E + 255) / 256, g);
    rgc_hist<<<egrid, 256, 0, stream>>>(dst, cnt8, N, E, g, rel0);
    int nchunks = NC * g * ntiles;
    rgc_chunksum<<<(nchunks + 3) / 4, 256, 0, stream>>>(cnt8, tcnt8, N, ntiles, nchunks);
    rgc_scan<<<1, 1024, 0, stream>>>(tcnt8, tptr8, nchunks, g * E);
    rgc_offsets<<<(nchunks + 3) / 4, 256, 0, stream>>>(cnt8, tptr8, off8, N, ntiles, nchunks);
    rgc_fill<<<egrid, 256, 0, stream>>>(src, dst, off8, esrc, N, E, g, rel0);
    dim3 agrid(ntiles, g);
    rgc_agg<<<agrid, 256, 0, stream>>>(xb, cnt8, off8, esrc, Ahat, N, ntiles, g);
    int flags = (rel0 == 0 ? 1 : 0) | (rel0 + g >= R ? 2 : 0);
    rgc_gemm<<<ntiles, 256, 0, stream>>>(xb, WT, Ahat, out, N, g, rel0, R, flags);
  }
}